// Round 7
// baseline (252.398 us; speedup 1.0000x reference)
//
#include <hip/hip_runtime.h>
#include <cstdint>
#include <cstddef>

#define EPSF 1e-5f
#define LEAKF 0.01f
#define AVGD 3.3f

static constexpr int Nn = 256, DIN = 128, DE = 64, Hn = 128;
static constexpr int BN = 2048;            // nodes
static constexpr int CTA = 640;            // Ab cols: [input(128) | m(512)]
static constexpr int CTW = 1664;           // post_W rows (full)

typedef short bf16x8 __attribute__((ext_vector_type(8)));
typedef float f32x4  __attribute__((ext_vector_type(4)));
union BF8 { bf16x8 v; uint16_t u[8]; };

__device__ __forceinline__ float bf2f(uint16_t u) { return __uint_as_float(((uint32_t)u) << 16); }
__device__ __forceinline__ float bflo(uint32_t u)  { return __uint_as_float(u << 16); }
__device__ __forceinline__ uint16_t f2bf(float f) {
  uint32_t u = __float_as_uint(f);
  u += 0x7fffu + ((u >> 16) & 1u);   // RNE
  return (uint16_t)(u >> 16);
}

// Per-block inline dtype probe (bf16 vs fp32 storage). Wave-uniform.
__device__ __forceinline__ int detect_bf16(const uint32_t* w) {
  float lo = bflo(w[threadIdx.x & 63]);
  unsigned long long ok = __ballot(fabsf(lo) < 64.f);
  return ok == 0xFFFFFFFFFFFFFFFFull;
}
__device__ __forceinline__ float loadf(const void* p, size_t i, int isbf) {
  return isbf ? bf2f(((const uint16_t*)p)[i]) : ((const float*)p)[i];
}
__device__ __forceinline__ f32x4 mfma16(bf16x8 a, bf16x8 b, f32x4 c) {
  return __builtin_amdgcn_mfma_f32_16x16x32_bf16(a, b, c, 0, 0, 0);
}

// ---------------- D1: prep + k1 (1080 blocks x 256 thr) — unchanged from R6 ----------------
__global__ __launch_bounds__(256) void k_prep(
    const void* __restrict__ input, const void* __restrict__ pre_W,
    const void* __restrict__ post_W, const void* __restrict__ mix_W,
    const void* __restrict__ Wih, const void* __restrict__ Whh,
    const void* __restrict__ hidden, const void* __restrict__ pre_b,
    uint16_t* __restrict__ preWTb, uint16_t* __restrict__ postTb,
    uint16_t* __restrict__ mixTb, uint16_t* __restrict__ Wihb,
    uint16_t* __restrict__ Whhb, uint16_t* __restrict__ hidb,
    uint16_t* __restrict__ Ab, float* __restrict__ hi, float* __restrict__ hj) {
  int isbf = detect_bf16((const uint32_t*)input);
  int b = blockIdx.x, tid = threadIdx.x;
  if (b < 264) {   // transposes (bf16 out, col-major)
    __shared__ float tile[32][33];
    const void* src; int R, C, t; uint16_t* bdst;
    if (b < 16)       { src = mix_W;  R = 128;  C = 128; t = b;       bdst = mixTb; }
    else if (b < 224) { src = post_W; R = 1664; C = 128; t = b - 16;  bdst = postTb; }
    else              { src = pre_W;  R = 320;  C = 128; t = b - 224; bdst = preWTb; }
    int bx = t & 3, by = t >> 2;
    int tx = tid & 31, ty = tid >> 5;          // 32 x 8
    int c0 = bx * 32, r0 = by * 32;
    #pragma unroll
    for (int dy = 0; dy < 32; dy += 8) {
      size_t idx = (size_t)(r0 + ty + dy) * C + (c0 + tx);
      tile[ty + dy][tx] = loadf(src, idx, isbf);
    }
    __syncthreads();
    #pragma unroll
    for (int dy = 0; dy < 32; dy += 8)
      bdst[(size_t)(c0 + ty + dy) * R + (r0 + tx)] = f2bf(tile[tx][ty + dy]);
  } else if (b < 440) {   // bf16 copies
    const void* src; uint16_t* dst; int base;
    if (b < 288)      { src = Wih;    dst = Wihb; base = (b - 264) * 2048; }
    else if (b < 312) { src = Whh;    dst = Whhb; base = (b - 288) * 2048; }
    else              { src = hidden; dst = hidb; base = (b - 312) * 2048; }
    int i = base + tid * 8;
    uint16_t v[8];
    if (isbf) *(uint4*)v = *(const uint4*)((const uint16_t*)src + i);
    else { const float* s = (const float*)src + i;
           #pragma unroll
           for (int e = 0; e < 8; e++) v[e] = f2bf(s[e]); }
    *(uint4*)(dst + i) = *(uint4*)v;
  } else if (b < 568) {   // input -> Ab[:, 0:128]
    int idx = (b - 440) * 2048 + tid * 8;
    int node = idx >> 7, col = idx & 127;
    uint16_t v[8];
    if (isbf) *(uint4*)v = *(const uint4*)((const uint16_t*)input + idx);
    else { const float* s = (const float*)input + idx;
           #pragma unroll
           for (int e = 0; e < 8; e++) v[e] = f2bf(s[e]); }
    *(uint4*)(Ab + (size_t)node * CTA + col) = *(uint4*)v;
  } else {   // k1: wave = one 16x16 tile of {hi|hj} (2048x256)
    int lane = tid & 63, w = tid >> 6;
    int wg = (b - 568) * 4 + w;               // 0..2047
    int rt = wg >> 4, nt = wg & 15;
    int ishj = nt >> 3, ct = nt & 7;
    int m16 = lane & 15, quad = lane >> 4;
    int col = ct * 16 + m16;
    int row = rt * 16 + m16;
    int kbase = ishj ? 128 : 0;
    f32x4 acc = {0.f, 0.f, 0.f, 0.f};
    #pragma unroll
    for (int kt = 0; kt < 4; kt++) {
      bf16x8 av;
      if (isbf) av = *(const bf16x8*)((const uint16_t*)input + (size_t)row * 128 + kt * 32 + quad * 8);
      else { const float* s = (const float*)input + (size_t)row * 128 + kt * 32 + quad * 8;
             BF8 t;
             #pragma unroll
             for (int e = 0; e < 8; e++) t.u[e] = f2bf(s[e]);
             av = t.v; }
      BF8 bb;
      #pragma unroll
      for (int j = 0; j < 8; j++) {
        size_t wi = (size_t)(kbase + kt * 32 + quad * 8 + j) * 128 + col;
        bb.u[j] = isbf ? ((const uint16_t*)pre_W)[wi] : f2bf(((const float*)pre_W)[wi]);
      }
      acc = mfma16(av, bb.v, acc);
    }
    float bias = ishj ? 0.f : loadf(pre_b, col, isbf);
    float* dst = ishj ? hj : hi;
    #pragma unroll
    for (int r = 0; r < 4; r++)
      dst[(size_t)(rt * 16 + quad * 4 + r) * 128 + col] = acc[r] + bias;
  }
}

// ---------------- D2: edge aggregation, LDS double-buffered af staging ----------------
// af rows read ONCE per block (shared by 4 waves); 1 barrier per 16-edge chunk.
__global__ __launch_bounds__(256) void k2_mfma(
    const void* __restrict__ input, const void* __restrict__ adj_raw,
    const void* __restrict__ af_raw,
    const float* __restrict__ hi, const float* __restrict__ hj,
    const uint16_t* __restrict__ preWTb, uint16_t* __restrict__ Ab,
    float* __restrict__ degw) {
  __shared__ int nbr[Nn];
  __shared__ int wcnt[4];
  __shared__ __align__(16) uint16_t buf[2][16 * 72];   // stride 72: 2-way banks (free)
  int isbf = detect_bf16((const uint32_t*)input);
  int bi = blockIdx.x, tid = threadIdx.x;
  int lane = tid & 63, w = tid >> 6;

  // ordered compaction of adjacency row via ballot (no atomics)
  float a = loadf(adj_raw, (size_t)bi * Nn + tid, isbf);
  unsigned long long bm = __ballot(a > 0.f);
  int pre = __popcll(bm & ((1ull << lane) - 1ull));
  if (lane == 0) wcnt[w] = __popcll(bm);
  __syncthreads();
  int base = 0, cnt = 0;
  #pragma unroll
  for (int i = 0; i < 4; i++) { if (i < w) base += wcnt[i]; cnt += wcnt[i]; }
  if (a > 0.f) nbr[base + pre] = tid;
  __syncthreads();

  int m16 = lane & 15, quad = lane >> 4;
  int col0 = w * 32 + m16, col1 = col0 + 16;

  // B fragments: We rows 256..319 of preWTb ([col][k], stride 320)
  bf16x8 b00 = *(const bf16x8*)&preWTb[(size_t)col0 * 320 + 256 + quad * 8];
  bf16x8 b01 = *(const bf16x8*)&preWTb[(size_t)col0 * 320 + 288 + quad * 8];
  bf16x8 b10 = *(const bf16x8*)&preWTb[(size_t)col1 * 320 + 256 + quad * 8];
  bf16x8 b11 = *(const bf16x8*)&preWTb[(size_t)col1 * 320 + 288 + quad * 8];

  float base0 = hi[(size_t)bi * 128 + col0];
  float base1 = hi[(size_t)bi * 128 + col1];
  const float* hjb = &hj[(size_t)(bi & ~(Nn - 1)) * 128];

  float s1a = 0.f, s2a = 0.f, mxa = -1e30f, mna = 1e30f;
  float s1b = 0.f, s2b = 0.f, mxb = -1e30f, mnb = 1e30f;

  // stage chunk ce into buf[sel]: 16 edge rows x 64 bf16 (tid<128: 16B each)
  auto stage = [&](int ce, int sel) {
    if (tid < 128) {
      int e = tid >> 3, seg = tid & 7;
      int ei = ce + e; if (ei >= cnt) ei = cnt - 1;
      int j = nbr[ei];
      uint16_t v[8];
      if (isbf)
        *(uint4*)v = *(const uint4*)((const uint16_t*)af_raw + ((size_t)bi * Nn + j) * DE + seg * 8);
      else {
        const float* s = (const float*)af_raw + ((size_t)bi * Nn + j) * DE + seg * 8;
        #pragma unroll
        for (int x = 0; x < 8; x++) v[x] = f2bf(s[x]);
      }
      *(uint4*)&buf[sel][e * 72 + seg * 8] = *(uint4*)v;
    }
  };

  if (cnt > 0) {
    stage(0, 0);
    __syncthreads();
    for (int ce = 0; ce < cnt; ce += 16) {
      int cur = (ce >> 4) & 1;
      if (ce + 16 < cnt) stage(ce + 16, cur ^ 1);
      float hjv0[4], hjv1[4]; int vld[4];
      #pragma unroll
      for (int r = 0; r < 4; r++) {
        int e = ce + quad * 4 + r;
        vld[r] = (e < cnt);
        int jj = nbr[vld[r] ? e : (cnt - 1)];
        hjv0[r] = hjb[(size_t)jj * 128 + col0];
        hjv1[r] = hjb[(size_t)jj * 128 + col1];
      }
      bf16x8 a0 = *(const bf16x8*)&buf[cur][m16 * 72 + quad * 8];
      bf16x8 a1 = *(const bf16x8*)&buf[cur][m16 * 72 + 32 + quad * 8];
      f32x4 C0 = {0.f,0.f,0.f,0.f}, C1 = C0;
      C0 = mfma16(a0, b00, C0); C0 = mfma16(a1, b01, C0);
      C1 = mfma16(a0, b10, C1); C1 = mfma16(a1, b11, C1);
      #pragma unroll
      for (int r = 0; r < 4; r++) {
        float h0 = base0 + hjv0[r] + C0[r];
        float h1 = base1 + hjv1[r] + C1[r];
        if (vld[r]) {
          s1a += h0; s2a += h0 * h0; mxa = fmaxf(mxa, h0); mna = fminf(mna, h0);
          s1b += h1; s2b += h1 * h1; mxb = fmaxf(mxb, h1); mnb = fminf(mnb, h1);
        }
      }
      __syncthreads();
    }
  }
  #pragma unroll
  for (int off = 16; off <= 32; off <<= 1) {
    s1a += __shfl_xor(s1a, off); s2a += __shfl_xor(s2a, off);
    mxa = fmaxf(mxa, __shfl_xor(mxa, off)); mna = fminf(mna, __shfl_xor(mna, off));
    s1b += __shfl_xor(s1b, off); s2b += __shfl_xor(s2b, off);
    mxb = fmaxf(mxb, __shfl_xor(mxb, off)); mnb = fminf(mnb, __shfl_xor(mnb, off));
  }
  if (tid == 0) degw[bi] = (float)cnt;
  if (quad == 0) {
    float degc = fmaxf((float)cnt, EPSF);
    uint16_t* mo = Ab + (size_t)bi * CTA + 128;
    #pragma unroll
    for (int t = 0; t < 2; t++) {
      float s1 = t ? s1b : s1a, s2 = t ? s2b : s2a;
      float mx = t ? mxb : mxa, mn = t ? mnb : mna;
      int col = t ? col1 : col0;
      float mean = s1 / degc;
      float var  = fmaxf(s2 / degc - mean * mean, 0.f);
      float stdv = sqrtf(var + EPSF);
      if (cnt == 0) { mx = 0.f; mn = 0.f; }
      mo[0*128+col] = f2bf(mean); mo[1*128+col] = f2bf(mx);
      mo[2*128+col] = f2bf(mn);   mo[3*128+col] = f2bf(stdv);
    }
  }
}

// ---------------- D3: fused post(K-factored) + mix + GRU (512 blocks x 256) ----------------
// Block = 4 real nodes, M=16 via row-duplication x4 (m16&3); 2 blocks/CU.
__global__ __launch_bounds__(256) void k3f(
    const uint16_t* __restrict__ Ab, const uint16_t* __restrict__ postTb,
    const void* __restrict__ post_b, const uint16_t* __restrict__ mixTb,
    const void* __restrict__ mix_b, const uint16_t* __restrict__ Wihb,
    const uint16_t* __restrict__ Whhb, const uint16_t* __restrict__ hidb,
    const float* __restrict__ degw, const void* __restrict__ input_flag,
    void* __restrict__ out) {
  constexpr int SX = 136;
  __shared__ __align__(16) uint16_t y_s[4 * SX];
  __shared__ __align__(16) uint16_t x_s[4 * SX];
  __shared__ __align__(16) uint16_t hid_s[4 * SX];
  int isbf = detect_bf16((const uint32_t*)input_flag);
  int tid = threadIdx.x;
  int n0 = blockIdx.x * 4;
  if (tid < 64) {
    int row = tid >> 4, c = (tid & 15) * 8;
    *(uint4*)&hid_s[row * SX + c] = *(const uint4*)&hidb[(size_t)(n0 + row) * 128 + c];
  }
  int lane = tid & 63, w = tid >> 6;
  int m16 = lane & 15, quad = lane >> 4;
  const uint16_t* ap = Ab + (size_t)(n0 + (m16 & 3)) * CTA + quad * 8;
  int col0 = (w * 2) * 16 + m16, col1 = (w * 2 + 1) * 16 + m16;
  const uint16_t* bp0 = postTb + (size_t)col0 * CTW + quad * 8;
  const uint16_t* bp1 = postTb + (size_t)col1 * CTW + quad * 8;

  f32x4 aX0 = {0.f,0.f,0.f,0.f}, aX1 = aX0;
  f32x4 a10 = aX0, a11 = aX0, a20 = aX0, a21 = aX0, a30 = aX0, a31 = aX0;
  #pragma unroll
  for (int kt = 0; kt < 4; kt++) {          // input part, K=128
    bf16x8 a = *(const bf16x8*)(ap + kt * 32);
    aX0 = mfma16(a, *(const bf16x8*)(bp0 + kt * 32), aX0);
    aX1 = mfma16(a, *(const bf16x8*)(bp1 + kt * 32), aX1);
  }
  #pragma unroll 4
  for (int kk = 0; kk < 16; kk++) {         // m part, K=512, 3 B-streams
    bf16x8 a = *(const bf16x8*)(ap + 128 + kk * 32);
    a10 = mfma16(a, *(const bf16x8*)(bp0 + 128  + kk * 32), a10);
    a20 = mfma16(a, *(const bf16x8*)(bp0 + 640  + kk * 32), a20);
    a30 = mfma16(a, *(const bf16x8*)(bp0 + 1152 + kk * 32), a30);
    a11 = mfma16(a, *(const bf16x8*)(bp1 + 128  + kk * 32), a11);
    a21 = mfma16(a, *(const bf16x8*)(bp1 + 640  + kk * 32), a21);
    a31 = mfma16(a, *(const bf16x8*)(bp1 + 1152 + kk * 32), a31);
  }
  float pb0 = loadf(post_b, col0, isbf), pb1 = loadf(post_b, col1, isbf);
  #pragma unroll
  for (int r = 0; r < 4; r++) {
    int row = quad * 4 + r;
    if (row < 4) {
      float deg = degw[n0 + row];
      float slog = logf(deg + 1.f) / AVGD;
      float inv  = 1.f / (slog + EPSF);
      y_s[row * SX + col0] = f2bf(aX0[r] + a10[r] + slog * a20[r] + inv * a30[r] + pb0);
      y_s[row * SX + col1] = f2bf(aX1[r] + a11[r] + slog * a21[r] + inv * a31[r] + pb1);
    }
  }
  __syncthreads();

  // ---- mix + leaky ----
  const uint16_t* ya = &y_s[(m16 & 3) * SX + quad * 8];
  const uint16_t* mb0 = mixTb + (size_t)col0 * 128 + quad * 8;
  const uint16_t* mb1 = mixTb + (size_t)col1 * 128 + quad * 8;
  f32x4 mm0 = {0.f,0.f,0.f,0.f}, mm1 = mm0;
  #pragma unroll
  for (int kt = 0; kt < 4; kt++) {
    bf16x8 a = *(const bf16x8*)(ya + kt * 32);
    mm0 = mfma16(a, *(const bf16x8*)(mb0 + kt * 32), mm0);
    mm1 = mfma16(a, *(const bf16x8*)(mb1 + kt * 32), mm1);
  }
  float mbias0 = loadf(mix_b, col0, isbf), mbias1 = loadf(mix_b, col1, isbf);
  #pragma unroll
  for (int r = 0; r < 4; r++) {
    int row = quad * 4 + r;
    if (row < 4) {
      float v0 = mm0[r] + mbias0; v0 = v0 > 0.f ? v0 : LEAKF * v0;
      float v1 = mm1[r] + mbias1; v1 = v1 > 0.f ? v1 : LEAKF * v1;
      x_s[row * SX + col0] = f2bf(v0);
      x_s[row * SX + col1] = f2bf(v1);
    }
  }
  __syncthreads();

  // ---- GRU ----
  f32x4 gi[3][2], gh[3][2];
  #pragma unroll
  for (int q = 0; q < 3; q++)
    #pragma unroll
    for (int t = 0; t < 2; t++) { gi[q][t] = {0.f,0.f,0.f,0.f}; gh[q][t] = {0.f,0.f,0.f,0.f}; }
  const uint16_t* xa = &x_s[(m16 & 3) * SX + quad * 8];
  const uint16_t* ha = &hid_s[(m16 & 3) * SX + quad * 8];
  #pragma unroll
  for (int kt = 0; kt < 4; kt++) {
    bf16x8 ax = *(const bf16x8*)(xa + kt * 32);
    bf16x8 ah = *(const bf16x8*)(ha + kt * 32);
    #pragma unroll
    for (int q = 0; q < 3; q++) {
      gi[q][0] = mfma16(ax, *(const bf16x8*)&Wihb[(size_t)(q * 128 + col0) * 128 + kt * 32 + quad * 8], gi[q][0]);
      gi[q][1] = mfma16(ax, *(const bf16x8*)&Wihb[(size_t)(q * 128 + col1) * 128 + kt * 32 + quad * 8], gi[q][1]);
      gh[q][0] = mfma16(ah, *(const bf16x8*)&Whhb[(size_t)(q * 128 + col0) * 128 + kt * 32 + quad * 8], gh[q][0]);
      gh[q][1] = mfma16(ah, *(const bf16x8*)&Whhb[(size_t)(q * 128 + col1) * 128 + kt * 32 + quad * 8], gh[q][1]);
    }
  }
  #pragma unroll
  for (int t = 0; t < 2; t++) {
    int col = t ? col1 : col0;
    #pragma unroll
    for (int r = 0; r < 4; r++) {
      int row = quad * 4 + r;
      if (row < 4) {
        float rg = 1.f / (1.f + expf(-(gi[0][t][r] + gh[0][t][r])));
        float zg = 1.f / (1.f + expf(-(gi[1][t][r] + gh[1][t][r])));
        float ng = tanhf(gi[2][t][r] + rg * gh[2][t][r]);
        float hv = bf2f(hid_s[row * SX + col]);
        float res = (1.f - zg) * ng + zg * hv;
        size_t oi = (size_t)(n0 + row) * 128 + col;
        if (isbf) ((uint16_t*)out)[oi] = f2bf(res);
        else      ((float*)out)[oi]    = res;
      }
    }
  }
}

extern "C" void kernel_launch(void* const* d_in, const int* in_sizes, int n_in,
                              void* d_out, int out_size, void* d_ws, size_t ws_size,
                              hipStream_t stream) {
  const void* input  = d_in[0];
  const void* adj    = d_in[1];
  const void* af     = d_in[2];
  const void* hidden = d_in[3];
  const void* pre_W  = d_in[4];
  const void* pre_b  = d_in[5];
  const void* post_W = d_in[6];
  const void* post_b = d_in[7];
  const void* mix_W  = d_in[8];
  const void* mix_b  = d_in[9];
  const void* Wih    = d_in[10];
  const void* Whh    = d_in[11];

  float* ws = (float*)d_ws;
  float* hi   = ws;                              // 262144 f
  float* hj   = hi + 262144;                     // 262144 f
  float* degw = hj + 262144;                     // 2048 f
  uint16_t* Ab     = (uint16_t*)(degw + 2048);   // 2048*640
  uint16_t* postTb = Ab + (size_t)BN * CTA;      // 212992
  uint16_t* mixTb  = postTb + 212992;            // 16384
  uint16_t* preWTb = mixTb + 16384;              // 40960
  uint16_t* Wihb   = preWTb + 40960;             // 49152
  uint16_t* Whhb   = Wihb + 49152;               // 49152
  uint16_t* hidb   = Whhb + 49152;               // 262144

  k_prep<<<1080, 256, 0, stream>>>(input, pre_W, post_W, mix_W, Wih, Whh, hidden, pre_b,
                                   preWTb, postTb, mixTb, Wihb, Whhb, hidb, Ab, hi, hj);
  k2_mfma<<<BN, 256, 0, stream>>>(input, adj, af, hi, hj, preWTb, Ab, degw);
  k3f<<<512, 256, 0, stream>>>(Ab, postTb, post_b, mixTb, mix_b,
                               Wihb, Whhb, hidb, degw, input, d_out);
}

// Round 8
// 228.130 us; speedup vs baseline: 1.1064x; 1.1064x over previous
//
#include <hip/hip_runtime.h>
#include <cstdint>
#include <cstddef>

#define EPSF 1e-5f
#define LEAKF 0.01f
#define AVGD 3.3f

static constexpr int Nn = 256, DIN = 128, DE = 64, Hn = 128;
static constexpr int BN = 2048;            // nodes
static constexpr int CT = 1664;            // [input(128) | m_ext(1536)]

typedef short bf16x8 __attribute__((ext_vector_type(8)));
typedef float f32x4  __attribute__((ext_vector_type(4)));
union BF8 { bf16x8 v; uint16_t u[8]; };

__device__ __forceinline__ float bf2f(uint16_t u) { return __uint_as_float(((uint32_t)u) << 16); }
__device__ __forceinline__ float bflo(uint32_t u)  { return __uint_as_float(u << 16); }
__device__ __forceinline__ uint16_t f2bf(float f) {
  uint32_t u = __float_as_uint(f);
  u += 0x7fffu + ((u >> 16) & 1u);   // RNE
  return (uint16_t)(u >> 16);
}

// Per-block inline dtype probe (bf16 vs fp32 storage). Wave-uniform.
__device__ __forceinline__ int detect_bf16(const uint32_t* w) {
  float lo = bflo(w[threadIdx.x & 63]);
  unsigned long long ok = __ballot(fabsf(lo) < 64.f);
  return ok == 0xFFFFFFFFFFFFFFFFull;
}
__device__ __forceinline__ float loadf(const void* p, size_t i, int isbf) {
  return isbf ? bf2f(((const uint16_t*)p)[i]) : ((const float*)p)[i];
}
__device__ __forceinline__ f32x4 mfma16(bf16x8 a, bf16x8 b, f32x4 c) {
  return __builtin_amdgcn_mfma_f32_16x16x32_bf16(a, b, c, 0, 0, 0);
}

// ---------------- prep: all weight/input reformatting, ONE dispatch ----------------
// b 0..15   : mixTb  (bf16 col-major transpose of mix_W 128x128)
// b 16..23  : spare
// b 24..231 : postTb (bf16 col-major transpose of post_W 1664x128)
// b 232..251: preWb  (bf16 copy of pre_W 320x128)
// b 252..275: Wihb   | b 276..299: Whhb   (bf16 copies 384x128)
// b 300..427: Ab[:,0:128] = bf16(input)
// b 428..555: hidb = bf16(hidden)
__global__ __launch_bounds__(256) void k_prep(
    const void* __restrict__ input, const void* __restrict__ pre_W,
    const void* __restrict__ post_W, const void* __restrict__ mix_W,
    const void* __restrict__ Wih, const void* __restrict__ Whh,
    const void* __restrict__ hidden,
    uint16_t* __restrict__ preWb, uint16_t* __restrict__ postTb,
    uint16_t* __restrict__ mixTb, uint16_t* __restrict__ Wihb,
    uint16_t* __restrict__ Whhb, uint16_t* __restrict__ hidb,
    uint16_t* __restrict__ Ab) {
  int isbf = detect_bf16((const uint32_t*)input);
  int b = blockIdx.x, tid = threadIdx.x;
  if (b < 232) {   // transposes (bf16 out)
    if (b >= 16 && b < 24) return;   // spare
    __shared__ float tile[32][33];
    const void* src; int off, R, C, t; uint16_t* bdst;
    if (b < 16)      { src = mix_W;  off = 0; bdst = mixTb;  R = 128;  C = 128; t = b; }
    else             { src = post_W; off = 0; bdst = postTb; R = 1664; C = 128; t = b - 24; }
    int bx = t & 3, by = t >> 2;
    int tx = tid & 31, ty = tid >> 5;          // 32 x 8
    int c0 = bx * 32, r0 = by * 32;
    #pragma unroll
    for (int dy = 0; dy < 32; dy += 8) {
      size_t idx = (size_t)off + (size_t)(r0 + ty + dy) * C + (c0 + tx);
      tile[ty + dy][tx] = loadf(src, idx, isbf);
    }
    __syncthreads();
    #pragma unroll
    for (int dy = 0; dy < 32; dy += 8)
      bdst[(size_t)(c0 + ty + dy) * R + (r0 + tx)] = f2bf(tile[tx][ty + dy]);
  } else if (b < 428 && b >= 300) {   // input -> Ab (strided rows)
    int idx = (b - 300) * 2048 + tid * 8;
    int node = idx >> 7, col = idx & 127;
    uint16_t v[8];
    if (isbf) *(uint4*)v = *(const uint4*)((const uint16_t*)input + idx);
    else { const float* s = (const float*)input + idx;
           #pragma unroll
           for (int e = 0; e < 8; e++) v[e] = f2bf(s[e]); }
    *(uint4*)(Ab + (size_t)node * CT + col) = *(uint4*)v;
  } else {         // plain bf16 copies
    const void* src; uint16_t* dst; int base;
    if (b < 252)      { src = pre_W;  dst = preWb; base = (b - 232) * 2048; }
    else if (b < 276) { src = Wih;    dst = Wihb;  base = (b - 252) * 2048; }
    else if (b < 300) { src = Whh;    dst = Whhb;  base = (b - 276) * 2048; }
    else              { src = hidden; dst = hidb;  base = (b - 428) * 2048; }
    int i = base + tid * 8;
    uint16_t v[8];
    if (isbf) *(uint4*)v = *(const uint4*)((const uint16_t*)src + i);
    else { const float* s = (const float*)src + i;
           #pragma unroll
           for (int e = 0; e < 8; e++) v[e] = f2bf(s[e]); }
    *(uint4*)(dst + i) = *(uint4*)v;
  }
}

// ---------------- k1: hi = input@Wi + pre_b ; hj = input@Wj (MFMA) ----------------
// 512 blocks x 4 waves; wave = one 16x16 tile of the 2048x256 {hi|hj} output.
__global__ __launch_bounds__(256) void k1_mfma(
    const uint16_t* __restrict__ Ab, const uint16_t* __restrict__ preWb,
    const void* __restrict__ pre_b, const void* __restrict__ input_flag,
    float* __restrict__ hi, float* __restrict__ hj) {
  int isbf = detect_bf16((const uint32_t*)input_flag);
  int tid = threadIdx.x;
  int lane = tid & 63, w = tid >> 6;
  int wg = blockIdx.x * 4 + w;              // 0..2047
  int rt = wg >> 4, nt = wg & 15;
  int ishj = nt >> 3, ct = nt & 7;
  int m16 = lane & 15, quad = lane >> 4;
  int col = ct * 16 + m16;
  const uint16_t* ap = Ab + (size_t)(rt * 16 + m16) * CT + quad * 8;
  int kbase = ishj ? 128 : 0;
  f32x4 acc = {0.f, 0.f, 0.f, 0.f};
  #pragma unroll
  for (int kt = 0; kt < 4; kt++) {
    bf16x8 a = *(const bf16x8*)(ap + kt * 32);
    BF8 bb;
    #pragma unroll
    for (int j = 0; j < 8; j++)
      bb.u[j] = preWb[(size_t)(kbase + kt * 32 + quad * 8 + j) * 128 + col];
    acc = mfma16(a, bb.v, acc);
  }
  float bias = ishj ? 0.f : loadf(pre_b, col, isbf);
  float* dst = ishj ? hj : hi;
  #pragma unroll
  for (int r = 0; r < 4; r++)
    dst[(size_t)(rt * 16 + quad * 4 + r) * 128 + col] = acc[r] + bias;
}

// ---------------- k2: edge aggregation via MFMA -> Ab[:, 128:1664] ----------------
// 1 block per node, 256 thr (4 waves). Chunks of 16 edges; wave w owns cols [32w,32w+32).
__global__ __launch_bounds__(256) void k2_mfma(
    const void* __restrict__ input, const void* __restrict__ adj_raw,
    const void* __restrict__ af_raw,
    const float* __restrict__ hi, const float* __restrict__ hj,
    const uint16_t* __restrict__ preWb, uint16_t* __restrict__ Ab) {
  __shared__ int s_cnt;
  __shared__ int nbr[Nn];
  __shared__ __align__(16) uint16_t A_lds[16 * 72];   // stride 72: 2-way banks (free)
  int isbf = detect_bf16((const uint32_t*)input);
  int bi = blockIdx.x, tid = threadIdx.x;
  if (tid == 0) s_cnt = 0;
  __syncthreads();
  {
    float a = loadf(adj_raw, (size_t)bi * Nn + tid, isbf);
    if (a > 0.f) nbr[atomicAdd(&s_cnt, 1)] = tid;
  }
  __syncthreads();
  int cnt = s_cnt;

  int lane = tid & 63, w = tid >> 6;
  int m16 = lane & 15, quad = lane >> 4;
  int col0 = w * 32 + m16, col1 = col0 + 16;

  // B fragments: We = preWb rows 256..319 (row-major = B[k][n] layout)
  BF8 b00, b01, b10, b11;   // [tile][kstep]
  #pragma unroll
  for (int j = 0; j < 8; j++) {
    int k0 = 256 + quad * 8 + j, k1 = k0 + 32;
    b00.u[j] = preWb[(size_t)k0 * 128 + col0];
    b01.u[j] = preWb[(size_t)k1 * 128 + col0];
    b10.u[j] = preWb[(size_t)k0 * 128 + col1];
    b11.u[j] = preWb[(size_t)k1 * 128 + col1];
  }
  float base0 = hi[(size_t)bi * 128 + col0];
  float base1 = hi[(size_t)bi * 128 + col1];
  const float* hjb = &hj[(size_t)(bi & ~(Nn - 1)) * 128];

  float s1a = 0.f, s2a = 0.f, mxa = -1e30f, mna = 1e30f;
  float s1b = 0.f, s2b = 0.f, mxb = -1e30f, mnb = 1e30f;

  for (int ce = 0; ce < cnt; ce += 16) {
    __syncthreads();                 // A_lds free from previous chunk
    if (tid < 128) {                 // stage 16 edge rows (clamped tail)
      int e = tid >> 3, seg = tid & 7;
      int ei = ce + e; if (ei >= cnt) ei = cnt - 1;
      int j = nbr[ei];
      uint16_t v[8];
      if (isbf)
        *(uint4*)v = *(const uint4*)((const uint16_t*)af_raw + ((size_t)bi * Nn + j) * DE + seg * 8);
      else {
        const float* s = (const float*)af_raw + ((size_t)bi * Nn + j) * DE + seg * 8;
        #pragma unroll
        for (int x = 0; x < 8; x++) v[x] = f2bf(s[x]);
      }
      *(uint4*)&A_lds[e * 72 + seg * 8] = *(uint4*)v;
    }
    __syncthreads();
    float hjv0[4], hjv1[4]; int vld[4];
    #pragma unroll
    for (int r = 0; r < 4; r++) {
      int e = ce + quad * 4 + r;
      vld[r] = (e < cnt);
      int j = nbr[vld[r] ? e : (cnt - 1)];
      hjv0[r] = hjb[(size_t)j * 128 + col0];
      hjv1[r] = hjb[(size_t)j * 128 + col1];
    }
    bf16x8 a0 = *(const bf16x8*)&A_lds[m16 * 72 + quad * 8];
    bf16x8 a1 = *(const bf16x8*)&A_lds[m16 * 72 + 32 + quad * 8];
    f32x4 C0 = {0.f,0.f,0.f,0.f}, C1 = C0;
    C0 = mfma16(a0, b00.v, C0); C0 = mfma16(a1, b01.v, C0);
    C1 = mfma16(a0, b10.v, C1); C1 = mfma16(a1, b11.v, C1);
    #pragma unroll
    for (int r = 0; r < 4; r++) {
      float h0 = base0 + hjv0[r] + C0[r];
      float h1 = base1 + hjv1[r] + C1[r];
      if (vld[r]) {
        s1a += h0; s2a += h0 * h0; mxa = fmaxf(mxa, h0); mna = fminf(mna, h0);
        s1b += h1; s2b += h1 * h1; mxb = fmaxf(mxb, h1); mnb = fminf(mnb, h1);
      }
    }
  }
  // cross-quad reduce: lanes {m16, +16, +32, +48} hold partials of the same col
  #pragma unroll
  for (int off = 16; off <= 32; off <<= 1) {
    s1a += __shfl_xor(s1a, off); s2a += __shfl_xor(s2a, off);
    mxa = fmaxf(mxa, __shfl_xor(mxa, off)); mna = fminf(mna, __shfl_xor(mna, off));
    s1b += __shfl_xor(s1b, off); s2b += __shfl_xor(s2b, off);
    mxb = fmaxf(mxb, __shfl_xor(mxb, off)); mnb = fminf(mnb, __shfl_xor(mnb, off));
  }
  if (quad == 0) {
    float deg = (float)cnt, degc = fmaxf(deg, EPSF);
    float slog = logf(deg + 1.f) / AVGD;
    float inv  = 1.f / (slog + EPSF);
    uint16_t* mo = Ab + (size_t)bi * CT + 128;
    #pragma unroll
    for (int t = 0; t < 2; t++) {
      float s1 = t ? s1b : s1a, s2 = t ? s2b : s2a;
      float mx = t ? mxb : mxa, mn = t ? mnb : mna;
      int col = t ? col1 : col0;
      float mean = s1 / degc;
      float var  = fmaxf(s2 / degc - mean * mean, 0.f);
      float stdv = sqrtf(var + EPSF);
      if (cnt == 0) { mx = 0.f; mn = 0.f; }
      mo[0*128+col]  = f2bf(mean);        mo[1*128+col]  = f2bf(mx);
      mo[2*128+col]  = f2bf(mn);          mo[3*128+col]  = f2bf(stdv);
      mo[4*128+col]  = f2bf(mean * slog); mo[5*128+col]  = f2bf(mx * slog);
      mo[6*128+col]  = f2bf(mn * slog);   mo[7*128+col]  = f2bf(stdv * slog);
      mo[8*128+col]  = f2bf(mean * inv);  mo[9*128+col]  = f2bf(mx * inv);
      mo[10*128+col] = f2bf(mn * inv);    mo[11*128+col] = f2bf(stdv * inv);
    }
  }
}

// ---------------- k3a: post GEMM y = [input|m]@post_W + post_b (MFMA) ----------------
// 256 blocks x 4 waves; wave = one 16x16 C-tile, K=1664, dual accumulator chains.
__global__ __launch_bounds__(256) void k3a(
    const uint16_t* __restrict__ Ab, const uint16_t* __restrict__ postTb,
    const void* __restrict__ post_b, const void* __restrict__ input_flag,
    uint16_t* __restrict__ yb) {
  int isbf = detect_bf16((const uint32_t*)input_flag);
  int tid = threadIdx.x;
  int lane = tid & 63, w = tid >> 6;
  int wg = blockIdx.x * 4 + w;              // 0..1023
  int rt = wg >> 3, ct = wg & 7;
  int m16 = lane & 15, quad = lane >> 4;
  const uint16_t* ap = Ab     + (size_t)(rt * 16 + m16) * CT + quad * 8;
  const uint16_t* bp = postTb + (size_t)(ct * 16 + m16) * CT + quad * 8;
  f32x4 acc0 = {0.f,0.f,0.f,0.f}, acc1 = acc0;
  #pragma unroll 4
  for (int kt = 0; kt < 52; kt += 2) {
    bf16x8 a0 = *(const bf16x8*)(ap + kt * 32);
    bf16x8 b0 = *(const bf16x8*)(bp + kt * 32);
    bf16x8 a1 = *(const bf16x8*)(ap + kt * 32 + 32);
    bf16x8 b1 = *(const bf16x8*)(bp + kt * 32 + 32);
    acc0 = mfma16(a0, b0, acc0);
    acc1 = mfma16(a1, b1, acc1);
  }
  int col = ct * 16 + m16;
  float pb = loadf(post_b, col, isbf);
  #pragma unroll
  for (int r = 0; r < 4; r++)
    yb[(size_t)(rt * 16 + quad * 4 + r) * 128 + col] = f2bf(acc0[r] + acc1[r] + pb);
}

// ---------------- k3b: mix+leaky -> GRU -> out (MFMA, fused) ----------------
// 128 blocks x 8 waves; block = 16 nodes; wave w owns col-tile w.
__global__ __launch_bounds__(512) void k3b(
    const uint16_t* __restrict__ yb, const uint16_t* __restrict__ mixTb,
    const void* __restrict__ mix_b, const uint16_t* __restrict__ Wihb,
    const uint16_t* __restrict__ Whhb, const uint16_t* __restrict__ hidb,
    const void* __restrict__ input_flag, void* __restrict__ out) {
  constexpr int SX = 136;
  __shared__ __align__(16) uint16_t x_s[16 * SX];
  __shared__ __align__(16) uint16_t hid_s[16 * SX];
  int isbf = detect_bf16((const uint32_t*)input_flag);
  int tid = threadIdx.x;
  int n0 = blockIdx.x * 16;
  if (tid < 256) {   // stage hidden (16 x 128 bf16)
    int row = tid >> 4, c = (tid & 15) * 8;
    *(uint4*)&hid_s[row * SX + c] = *(const uint4*)&hidb[(size_t)(n0 + row) * 128 + c];
  }
  int lane = tid & 63, w = tid >> 6;
  int m16 = lane & 15, quad = lane >> 4;
  int col = w * 16 + m16;

  // mix GEMM (A = y from global)
  f32x4 acc = {0.f,0.f,0.f,0.f};
  const uint16_t* ya = yb    + (size_t)(n0 + m16) * 128 + quad * 8;
  const uint16_t* mb = mixTb + (size_t)col * 128 + quad * 8;
  #pragma unroll
  for (int kt = 0; kt < 4; kt++)
    acc = mfma16(*(const bf16x8*)(ya + kt * 32), *(const bf16x8*)(mb + kt * 32), acc);
  float mbias = loadf(mix_b, col, isbf);
  __syncthreads();
  #pragma unroll
  for (int r = 0; r < 4; r++) {
    float v = acc[r] + mbias; v = v > 0.f ? v : LEAKF * v;
    x_s[(quad * 4 + r) * SX + col] = f2bf(v);
  }
  __syncthreads();

  // GRU
  f32x4 gi[3], gh[3];
  #pragma unroll
  for (int q = 0; q < 3; q++) { gi[q] = {0.f,0.f,0.f,0.f}; gh[q] = {0.f,0.f,0.f,0.f}; }
  const uint16_t* xa = &x_s[m16 * SX + quad * 8];
  const uint16_t* ha = &hid_s[m16 * SX + quad * 8];
  #pragma unroll
  for (int kt = 0; kt < 4; kt++) {
    bf16x8 ax = *(const bf16x8*)(xa + kt * 32);
    bf16x8 ah = *(const bf16x8*)(ha + kt * 32);
    #pragma unroll
    for (int q = 0; q < 3; q++) {
      bf16x8 bi = *(const bf16x8*)&Wihb[(size_t)(q * 128 + col) * 128 + kt * 32 + quad * 8];
      bf16x8 bh = *(const bf16x8*)&Whhb[(size_t)(q * 128 + col) * 128 + kt * 32 + quad * 8];
      gi[q] = mfma16(ax, bi, gi[q]);
      gh[q] = mfma16(ah, bh, gh[q]);
    }
  }
  #pragma unroll
  for (int r = 0; r < 4; r++) {
    int row = quad * 4 + r;
    float rg = 1.f / (1.f + expf(-(gi[0][r] + gh[0][r])));
    float zg = 1.f / (1.f + expf(-(gi[1][r] + gh[1][r])));
    float ng = tanhf(gi[2][r] + rg * gh[2][r]);
    float hv = bf2f(hid_s[row * SX + col]);
    float res = (1.f - zg) * ng + zg * hv;
    size_t oi = (size_t)(n0 + row) * 128 + col;
    if (isbf) ((uint16_t*)out)[oi] = f2bf(res);
    else      ((float*)out)[oi]    = res;
  }
}

extern "C" void kernel_launch(void* const* d_in, const int* in_sizes, int n_in,
                              void* d_out, int out_size, void* d_ws, size_t ws_size,
                              hipStream_t stream) {
  const void* input  = d_in[0];
  const void* adj    = d_in[1];
  const void* af     = d_in[2];
  const void* hidden = d_in[3];
  const void* pre_W  = d_in[4];
  const void* pre_b  = d_in[5];
  const void* post_W = d_in[6];
  const void* post_b = d_in[7];
  const void* mix_W  = d_in[8];
  const void* mix_b  = d_in[9];
  const void* Wih    = d_in[10];
  const void* Whh    = d_in[11];

  float* ws = (float*)d_ws;
  float* hi = ws;                         // 262144 f
  float* hj = hi + 262144;                // 262144 f
  uint16_t* Ab     = (uint16_t*)(hj + 262144);   // 2048*1664
  uint16_t* postTb = Ab + (size_t)BN * CT;       // 212992
  uint16_t* mixTb  = postTb + 212992;            // 16384
  uint16_t* preWb  = mixTb + 16384;              // 40960
  uint16_t* Wihb   = preWb + 40960;              // 49152
  uint16_t* Whhb   = Wihb + 49152;               // 49152
  uint16_t* hidb   = Whhb + 49152;               // 262144
  uint16_t* yb     = hidb + 262144;              // 262144

  k_prep<<<556, 256, 0, stream>>>(input, pre_W, post_W, mix_W, Wih, Whh, hidden,
                                  preWb, postTb, mixTb, Wihb, Whhb, hidb, Ab);
  k1_mfma<<<512, 256, 0, stream>>>(Ab, preWb, pre_b, input, hi, hj);
  k2_mfma<<<BN, 256, 0, stream>>>(input, adj, af, hi, hj, preWb, Ab);
  k3a<<<256, 256, 0, stream>>>(Ab, postTb, post_b, input, yb);
  k3b<<<128, 512, 0, stream>>>(yb, mixTb, mix_b, Wihb, Whhb, hidb, input, d_out);
}